// Round 11
// baseline (111.516 us; speedup 1.0000x reference)
//
#include <hip/hip_runtime.h>
#include <hip/hip_bf16.h>
#include <math.h>

#define BB 32
#define TT 512
#define SS 128
#define CC 30
#define WW 10
#define DCTX 768
#define DENT 300
#define HH 100
#define EPSF 1e-5f
#define NEGF -1e30f

typedef __attribute__((ext_vector_type(8))) short bf16x8;
typedef __attribute__((ext_vector_type(4))) float f32x4;

#define NK  (DCTX / 32)        // 24 K-steps
#define NCT 20                 // col-tiles of 16 (320 cols >= 300)

// ---- DPP wave64 reduction: 6 VALU ops + readlane, NO DS traffic ----------
template<int C, int M>
__device__ __forceinline__ float dppadd(float x) {
    union { float f; int i; } u, r;
    u.f = x;
    r.i = __builtin_amdgcn_update_dpp(0, u.i, C, M, 0xf, true);
    return x + r.f;
}
__device__ __forceinline__ float wave_red(float x) {
    x = dppadd<0x111, 0xf>(x);   // row_shr:1
    x = dppadd<0x112, 0xf>(x);   // row_shr:2
    x = dppadd<0x114, 0xf>(x);   // row_shr:4
    x = dppadd<0x118, 0xf>(x);   // row_shr:8
    x = dppadd<0x142, 0xa>(x);   // row_bcast:15 -> rows 1,3
    x = dppadd<0x143, 0xc>(x);   // row_bcast:31 -> rows 2,3
    union { float f; int i; } u; u.f = x;
    u.i = __builtin_amdgcn_readlane(u.i, 63);
    return u.f;                  // uniform across the wave
}

__device__ __forceinline__ ushort f2bf(float f) {
    __hip_bfloat16 h = __float2bfloat16(f);
    return *reinterpret_cast<ushort*>(&h);
}

__device__ __forceinline__ float dot4(float4 a, float4 b) {
    return a.x*b.x + a.y*b.y + a.z*b.z + a.w*b.w;
}
__device__ __forceinline__ float hadd8(float4 a, float4 b) {
    return a.x+a.y+a.z+a.w + b.x+b.y+b.z+b.w;
}
__device__ __forceinline__ ushort4 cvt4(float4 v) {
    ushort4 h; h.x = f2bf(v.x); h.y = f2bf(v.y); h.z = f2bf(v.z); h.w = f2bf(v.w);
    return h;
}

// ---------------------------------------------------------------------------
// K0: proj_W (300x768 f32) -> frag-major bf16 (zero-padded cols 300..319).
// ---------------------------------------------------------------------------
__global__ __launch_bounds__(256) void wpre_kernel(
    const float* __restrict__ Wt, ushort* __restrict__ wpre)
{
    const int g = blockIdx.x * 256 + threadIdx.x;   // 0 .. NCT*NK*64-1
    const int l = g & 63;
    const int t = (g >> 6) % NK;
    const int ct = g / (NK * 64);
    const int col = ct * 16 + (l & 15);
    const int k = t * 32 + (l >> 4) * 8;
    ushort4 h0 = {0, 0, 0, 0}, h1 = {0, 0, 0, 0};
    if (col < DENT) {
        h0 = cvt4(*(const float4*)(Wt + (size_t)col * DCTX + k));
        h1 = cvt4(*(const float4*)(Wt + (size_t)col * DCTX + k + 4));
    }
    *(ushort4*)(wpre + (size_t)g * 8)     = h0;
    *(ushort4*)(wpre + (size_t)g * 8 + 4) = h1;
}

// ---------------------------------------------------------------------------
// K1: proj = ctx @ proj_W.T + proj_b -- hybrid MFMA GEMM (R6/R9, proven).
// BM=64, 512 threads. A: f32->LDS dbuf, depth-2 reg prefetch. B: frag-direct.
// ---------------------------------------------------------------------------
#define GBM 64
#define LDA 40

__global__ __launch_bounds__(512) void gemm_proj_mfma(
    const float*  __restrict__ A,     // (16384, 768)
    const ushort* __restrict__ wpre,  // frag-major bf16 W
    const float*  __restrict__ bias,  // (300)
    float* __restrict__ out)          // (16384, 300)
{
    __shared__ ushort Al[2][GBM * LDA];
    const int tid = threadIdx.x;
    const int lane = tid & 63;
    const int wv = tid >> 6;
    const int wm = wv >> 2;          // 0..1
    const int wn = wv & 3;           // 0..3
    const int m0 = blockIdx.x * GBM;
    const int ar = tid >> 3;         // 0..63
    const int ak = (tid & 7) * 4;    // 0..28
    const int lr = lane & 15;
    const int kq = (lane >> 4) * 8;

    const float* aP = A + (size_t)(m0 + ar) * DCTX + ak;
    const ushort* bp = wpre + (size_t)wn * 5 * NK * 512 + (size_t)lane * 8;

    f32x4 acc[2][5];
    #pragma unroll
    for (int i = 0; i < 2; ++i)
        #pragma unroll
        for (int j = 0; j < 5; ++j)
            acc[i][j] = (f32x4){0.f, 0.f, 0.f, 0.f};

    bf16x8 cb[5], nb[5];
    #pragma unroll
    for (int j = 0; j < 5; ++j)
        cb[j] = *(const bf16x8*)(bp + (size_t)j * NK * 512);

#define STOREA(BUF, v_) (*(ushort4*)&Al[BUF][ar * LDA + ak] = cvt4(v_))

#define COMPUTE(BUF) do {                                                      \
        bf16x8 af_[2];                                                         \
        _Pragma("unroll")                                                      \
        for (int i_ = 0; i_ < 2; ++i_)                                         \
            af_[i_] = *(const bf16x8*)&Al[BUF][(wm*32 + i_*16 + lr)*LDA + kq]; \
        _Pragma("unroll")                                                      \
        for (int j_ = 0; j_ < 5; ++j_)                                         \
            acc[0][j_] = __builtin_amdgcn_mfma_f32_16x16x32_bf16(              \
                af_[0], cb[j_], acc[0][j_], 0, 0, 0);                          \
        _Pragma("unroll")                                                      \
        for (int j_ = 0; j_ < 5; ++j_)                                         \
            acc[1][j_] = __builtin_amdgcn_mfma_f32_16x16x32_bf16(              \
                af_[1], cb[j_], acc[1][j_], 0, 0, 0);                          \
    } while (0)

    float4 avA = *(const float4*)(aP);
    float4 avB = *(const float4*)(aP + 32);
    STOREA(0, avA);
    __syncthreads();

    #pragma unroll 1
    for (int kk = 0; kk < NK; kk += 2) {
        #pragma unroll
        for (int j = 0; j < 5; ++j)
            nb[j] = *(const bf16x8*)(bp + ((size_t)j * NK + kk + 1) * 512);
        if (kk + 2 < NK) avA = *(const float4*)(aP + (kk + 2) * 32);
        COMPUTE(0);
        STOREA(1, avB);
        __syncthreads();
        #pragma unroll
        for (int j = 0; j < 5; ++j) cb[j] = nb[j];
        if (kk + 2 < NK) {
            #pragma unroll
            for (int j = 0; j < 5; ++j)
                nb[j] = *(const bf16x8*)(bp + ((size_t)j * NK + kk + 2) * 512);
            avB = *(const float4*)(aP + (kk + 3) * 32);
        }
        COMPUTE(1);
        if (kk + 2 < NK) STOREA(0, avA);
        __syncthreads();
        #pragma unroll
        for (int j = 0; j < 5; ++j) cb[j] = nb[j];
    }

    const int lq = lane >> 4;
    #pragma unroll
    for (int j = 0; j < 5; ++j) {
        int col = wn * 80 + j * 16 + lr;
        if (col < DENT) {
            float bv = bias[col];
            #pragma unroll
            for (int i = 0; i < 2; ++i)
                #pragma unroll
                for (int r = 0; r < 4; ++r) {
                    int row = m0 + wm * 32 + i * 16 + lq * 4 + r;
                    out[(size_t)row * DENT + col] = acc[i][j][r] + bv;
                }
        }
    }
}

// ---------------------------------------------------------------------------
// K2: span extraction + LN (DPP reductions). 4 spans/block. (R9, proven)
// ---------------------------------------------------------------------------
__global__ __launch_bounds__(256) void span_kernel(
    const float* __restrict__ proj,     // (B*T, 300)
    const int*   __restrict__ spans,    // (B*S, 2)
    const float* __restrict__ attn_W,   // (300)
    const float* __restrict__ attn_b,   // (1)
    const float* __restrict__ ln_g,
    const float* __restrict__ ln_b,
    const float* __restrict__ kg_g,
    const float* __restrict__ kg_b,
    float* __restrict__ srg_out,        // (B*S, 300)
    float* __restrict__ sgsb)           // (B*S, 2)
{
    const int bs = blockIdx.x * 4 + (threadIdx.x >> 6);
    const int b = bs >> 7;   // SS = 128
    const int lane = threadIdx.x & 63;
    const int start = spans[bs * 2 + 0];
    const int end   = spans[bs * 2 + 1];
    const int width = end - start;
    const bool lo = lane < 11;
    const float4 z = make_float4(0.f, 0.f, 0.f, 0.f);

    const float4* attW4 = (const float4*)attn_W;
    float4 w0 = attW4[lane];
    float4 w1 = lo ? attW4[64 + lane] : z;

    float4 a0[WW], a1[WW];
    float slog[WW];
    bool vld[WW];
    #pragma unroll
    for (int w = 0; w < WW; ++w) {
        int idx = start + w;
        vld[w] = (w <= width) && (idx >= 0) && (idx < TT);
        const float4* pr = (const float4*)(proj + (size_t)(b * TT + (vld[w] ? idx : 0)) * DENT);
        a0[w] = pr[lane];
        a1[w] = lo ? pr[64 + lane] : z;
        slog[w] = dot4(a0[w], w0) + dot4(a1[w], w1);
    }
    const float ab = attn_b[0];
    #pragma unroll
    for (int w = 0; w < WW; ++w) {
        float r = wave_red(slog[w]);
        slog[w] = vld[w] ? r + ab : NEGF;
    }
    float m = slog[0];
    #pragma unroll
    for (int w = 1; w < WW; ++w) m = fmaxf(m, slog[w]);
    float den = 0.f;
    float aw[WW];
    #pragma unroll
    for (int w = 0; w < WW; ++w) { aw[w] = expf(slog[w] - m); den += aw[w]; }
    const float inv = 1.f / den;
    const float msk = (start > -1) ? inv : 0.f;

    float4 acc0 = z, acc1 = z;
    #pragma unroll
    for (int w = 0; w < WW; ++w) {
        float c = aw[w] * msk;
        acc0.x = fmaf(c, a0[w].x, acc0.x); acc0.y = fmaf(c, a0[w].y, acc0.y);
        acc0.z = fmaf(c, a0[w].z, acc0.z); acc0.w = fmaf(c, a0[w].w, acc0.w);
        acc1.x = fmaf(c, a1[w].x, acc1.x); acc1.y = fmaf(c, a1[w].y, acc1.y);
        acc1.z = fmaf(c, a1[w].z, acc1.z); acc1.w = fmaf(c, a1[w].w, acc1.w);
    }
    float s1 = wave_red(hadd8(acc0, acc1));
    float s2 = wave_red(dot4(acc0, acc0) + dot4(acc1, acc1));
    const float mu = s1 * (1.f / DENT);
    const float rstd = rsqrtf(s2 * (1.f / DENT) - mu * mu + EPSF);

    const float4* lg4 = (const float4*)ln_g;  const float4* lb4 = (const float4*)ln_b;
    const float4* gg4 = (const float4*)kg_g;  const float4* gb4 = (const float4*)kg_b;
    float pg = 0.f, pb = 0.f;
    float4* so = (float4*)(srg_out + (size_t)bs * DENT);
    {
        float4 g = lg4[lane], bb_ = lb4[lane], gg = gg4[lane], gb = gb4[lane];
        float4 val;
        val.x = fmaf((acc0.x - mu) * rstd, g.x, bb_.x);
        val.y = fmaf((acc0.y - mu) * rstd, g.y, bb_.y);
        val.z = fmaf((acc0.z - mu) * rstd, g.z, bb_.z);
        val.w = fmaf((acc0.w - mu) * rstd, g.w, bb_.w);
        float4 vg = make_float4(val.x * gg.x, val.y * gg.y, val.z * gg.z, val.w * gg.w);
        so[lane] = vg;
        pg += vg.x + vg.y + vg.z + vg.w;
        pb += val.x * gb.x + val.y * gb.y + val.z * gb.z + val.w * gb.w;
    }
    if (lo) {
        float4 g = lg4[64 + lane], bb_ = lb4[64 + lane], gg = gg4[64 + lane], gb = gb4[64 + lane];
        float4 val;
        val.x = fmaf((acc1.x - mu) * rstd, g.x, bb_.x);
        val.y = fmaf((acc1.y - mu) * rstd, g.y, bb_.y);
        val.z = fmaf((acc1.z - mu) * rstd, g.z, bb_.z);
        val.w = fmaf((acc1.w - mu) * rstd, g.w, bb_.w);
        float4 vg = make_float4(val.x * gg.x, val.y * gg.y, val.z * gg.z, val.w * gg.w);
        so[64 + lane] = vg;
        pg += vg.x + vg.y + vg.z + vg.w;
        pb += val.x * gb.x + val.y * gb.y + val.z * gb.z + val.w * gb.w;
    }
    pg = wave_red(pg);
    pb = wave_red(pb);
    if (lane == 0) { sgsb[bs * 2 + 0] = pg; sgsb[bs * 2 + 1] = pb; }
}

// ---------------------------------------------------------------------------
// K3a: ONE WAVE PER (bs, c). No barriers, no LDS, ~50 VGPR -> 8 waves/SIMD.
// 4 waves/block share one bs (srg row L1-hot). Gathers issued wall-to-wall.
// score = (rstd*(s3 - mu*SG) + SB)/sqrt(D); MLP; stats = {mu, rstd, link}.
// ---------------------------------------------------------------------------
__global__ __launch_bounds__(256) void score_kernel(
    const float* __restrict__ srg,      // (B*S, 300)
    const float* __restrict__ sgsb,     // (B*S, 2)
    const int*   __restrict__ cand,     // (B*S*30)
    const float* __restrict__ priors,   // (B*S*30)
    const float* __restrict__ table,    // (V, 300)
    const float* __restrict__ W1,       // (100,2)
    const float* __restrict__ b1,       // (100)
    const float* __restrict__ W2,       // (100)
    const float* __restrict__ b2,       // (1)
    float*  __restrict__ out_link,      // (B*S*30)
    float4* __restrict__ stats)         // (B*S*30): mu, rstd, link
{
    const int lane = threadIdx.x & 63;
    const int wv = threadIdx.x >> 6;      // 0..3
    const int bs = blockIdx.x >> 3;       // 0..4095
    const int cg = blockIdx.x & 7;        // 0..7
    const int c  = cg * 4 + wv;           // 0..31
    const bool act = c < CC;
    const int q = bs * CC + (act ? c : 0);
    const bool lo = lane < 11;
    const float4 z = make_float4(0.f, 0.f, 0.f, 0.f);

    const int e = cand[q];
    const float prior = priors[q];
    const float4* row = (const float4*)(table + (size_t)e * DENT);
    float4 xa = row[lane];
    float4 xb = lo ? row[64 + lane] : z;

    const float4* sg4 = (const float4*)(srg + (size_t)bs * DENT);
    float4 g0 = sg4[lane];
    float4 g1 = lo ? sg4[64 + lane] : z;
    const float SG = sgsb[bs * 2 + 0];
    const float SB = sgsb[bs * 2 + 1];

    const float W1a0 = W1[2 * lane], W1b0 = W1[2 * lane + 1];
    const float B10 = b1[lane], W20 = W2[lane];
    float W1a1 = 0.f, W1b1 = 0.f, B11 = 0.f, W21 = 0.f;
    if (lane < HH - 64) {
        int j = lane + 64;
        W1a1 = W1[2 * j]; W1b1 = W1[2 * j + 1]; B11 = b1[j]; W21 = W2[j];
    }
    const float b2v = b2[0];

    float s1 = wave_red(hadd8(xa, xb));
    float s2 = wave_red(dot4(xa, xa) + dot4(xb, xb));
    float s3 = wave_red(dot4(g0, xa) + dot4(g1, xb));

    const float mu = s1 * (1.f / DENT);
    const float rstd = rsqrtf(s2 * (1.f / DENT) - mu * mu + EPSF);
    const float score = (rstd * (s3 - mu * SG) + SB) * rsqrtf((float)DENT);

    float h  = fmaxf(fmaf(W1a0, score, fmaf(W1b0, prior, B10)), 0.f);
    float h2 = fmaxf(fmaf(W1a1, score, fmaf(W1b1, prior, B11)), 0.f);
    float lp = wave_red(fmaf(W21, h2, W20 * h)) + b2v;
    const float link = (e > 0) ? lp : -10000.0f;

    if (act && lane == 0) {
        out_link[q] = link;
        stats[q] = make_float4(mu, rstd, link, 0.f);
    }
}

// ---------------------------------------------------------------------------
// K3b: per-(b,s): softmax over C=30 links, weighted entity sum.
// out[d] = g[d]*(sum_c coef_c*x_cd - sum_c coef_c*mu_c) + b[d]*sum_c n_c
// 320 threads; thread d owns one dim; 30 coalesced (L2/L3-warm) row reads.
// ---------------------------------------------------------------------------
__global__ __launch_bounds__(320) void weighted_kernel(
    const int*    __restrict__ cand,
    const float4* __restrict__ stats,
    const float*  __restrict__ table,
    const float*  __restrict__ kg_g,
    const float*  __restrict__ kg_b,
    float* __restrict__ out_w)          // (B*S, 300)
{
    __shared__ float ssc[CC], smu[CC], srs[CC], sexp[CC];
    __shared__ int sid[CC];
    const int bs = blockIdx.x;
    const int tid = threadIdx.x;
    if (tid < CC) {
        float4 st = stats[bs * CC + tid];
        smu[tid] = st.x; srs[tid] = st.y; ssc[tid] = st.z;
        sid[tid] = cand[bs * CC + tid];
    }
    __syncthreads();
    if (tid < CC) {
        float m = ssc[0];
        #pragma unroll
        for (int c = 1; c < CC; ++c) m = fmaxf(m, ssc[c]);
        sexp[tid] = expf(ssc[tid] - m);
    }
    __syncthreads();

    const int d = tid;
    if (d < DENT) {
        float den = 0.f;
        #pragma unroll
        for (int c = 0; c < CC; ++c) den += sexp[c];
        const float inv = 1.f / den;
        float coef[CC];
        float S2 = 0.f, sn = 0.f;
        #pragma unroll
        for (int c = 0; c < CC; ++c) {
            float n = sexp[c] * inv;
            coef[c] = n * srs[c];
            S2 = fmaf(coef[c], smu[c], S2);
            sn += n;
        }
        float acc = 0.f;
        #pragma unroll
        for (int c = 0; c < CC; ++c)
            acc = fmaf(coef[c], table[(size_t)sid[c] * DENT + d], acc);
        out_w[(size_t)bs * DENT + d] = kg_g[d] * (acc - S2) + kg_b[d] * sn;
    }
}

extern "C" void kernel_launch(void* const* d_in, const int* in_sizes, int n_in,
                              void* d_out, int out_size, void* d_ws, size_t ws_size,
                              hipStream_t stream) {
    const float* ctx    = (const float*)d_in[0];
    const int*   spans  = (const int*)d_in[2];
    const int*   cand   = (const int*)d_in[3];
    const float* priors = (const float*)d_in[4];
    const float* table  = (const float*)d_in[6];
    const float* projW  = (const float*)d_in[7];
    const float* projb  = (const float*)d_in[8];
    const float* kg_g   = (const float*)d_in[9];
    const float* kg_b   = (const float*)d_in[10];
    const float* ln_g   = (const float*)d_in[11];
    const float* ln_b   = (const float*)d_in[12];
    const float* attW   = (const float*)d_in[13];
    const float* attb   = (const float*)d_in[14];
    const float* W1     = (const float*)d_in[15];
    const float* b1     = (const float*)d_in[16];
    const float* W2     = (const float*)d_in[17];
    const float* b2     = (const float*)d_in[18];

    float* proj = (float*)d_ws;                           // (B*T, 300)
    float* srg  = proj + (size_t)BB * TT * DENT;          // (B*S, 300)
    float* sgsb = srg + (size_t)BB * SS * DENT;           // (B*S, 2)
    // wpre (492 KB) aliases srg: consumed by gemm before span writes srg.
    ushort* wpre = (ushort*)srg;
    // stats (1.97 MB) aliases proj: proj is dead after span_kernel, and
    // score_kernel (stats writer) runs after span_kernel (same stream).
    float4* stats = (float4*)d_ws;

    float* out_link = (float*)d_out;                      // (B*S*30)
    float* out_w    = out_link + (size_t)BB * SS * CC;    // (B*S, 300)

    wpre_kernel<<<NCT * NK * 64 / 256, 256, 0, stream>>>(projW, wpre);
    gemm_proj_mfma<<<BB * TT / GBM, 512, 0, stream>>>(ctx, wpre, projb, proj);
    span_kernel<<<BB * SS / 4, 256, 0, stream>>>(proj, spans, attW, attb,
                                                 ln_g, ln_b, kg_g, kg_b, srg, sgsb);
    score_kernel<<<BB * SS * 8, 256, 0, stream>>>(srg, sgsb, cand, priors, table,
                                                  W1, b1, W2, b2, out_link, stats);
    weighted_kernel<<<BB * SS, 320, 0, stream>>>(cand, stats, table, kg_g, kg_b, out_w);
}

// Round 12
// 81.960 us; speedup vs baseline: 1.3606x; 1.3606x over previous
//
#include <hip/hip_runtime.h>
#include <hip/hip_bf16.h>
#include <math.h>

#define BB 32
#define TT 512
#define SS 128
#define CC 30
#define WW 10
#define DCTX 768
#define DENT 300
#define HH 100
#define EPSF 1e-5f
#define NEGF -1e30f

typedef __attribute__((ext_vector_type(8))) short bf16x8;
typedef __attribute__((ext_vector_type(4))) float f32x4;

#define NK  (DCTX / 32)        // 24 K-steps
#define NCT 20                 // col-tiles of 16 (320 cols >= 300)

// ---- DPP wave64 reduction: 6 VALU ops + readlane, NO DS traffic ----------
template<int C, int M>
__device__ __forceinline__ float dppadd(float x) {
    union { float f; int i; } u, r;
    u.f = x;
    r.i = __builtin_amdgcn_update_dpp(0, u.i, C, M, 0xf, true);
    return x + r.f;
}
__device__ __forceinline__ float wave_red(float x) {
    x = dppadd<0x111, 0xf>(x);   // row_shr:1
    x = dppadd<0x112, 0xf>(x);   // row_shr:2
    x = dppadd<0x114, 0xf>(x);   // row_shr:4
    x = dppadd<0x118, 0xf>(x);   // row_shr:8
    x = dppadd<0x142, 0xa>(x);   // row_bcast:15 -> rows 1,3
    x = dppadd<0x143, 0xc>(x);   // row_bcast:31 -> rows 2,3
    union { float f; int i; } u; u.f = x;
    u.i = __builtin_amdgcn_readlane(u.i, 63);
    return u.f;                  // uniform across the wave
}

// ---- async global->LDS DMA, 16 B per lane (dest = uniform base + lane*16) -
__device__ __forceinline__ void dma16(const float* g, float* l) {
    __builtin_amdgcn_global_load_lds(
        (const __attribute__((address_space(1))) void*)g,
        (__attribute__((address_space(3))) void*)l, 16, 0, 0);
}

__device__ __forceinline__ ushort f2bf(float f) {
    __hip_bfloat16 h = __float2bfloat16(f);
    return *reinterpret_cast<ushort*>(&h);
}

__device__ __forceinline__ float dot4(float4 a, float4 b) {
    return a.x*b.x + a.y*b.y + a.z*b.z + a.w*b.w;
}
__device__ __forceinline__ float hadd8(float4 a, float4 b) {
    return a.x+a.y+a.z+a.w + b.x+b.y+b.z+b.w;
}
__device__ __forceinline__ ushort4 cvt4(float4 v) {
    ushort4 h; h.x = f2bf(v.x); h.y = f2bf(v.y); h.z = f2bf(v.z); h.w = f2bf(v.w);
    return h;
}

// ---------------------------------------------------------------------------
// K0: proj_W (300x768 f32) -> frag-major bf16 (zero-padded cols 300..319).
// ---------------------------------------------------------------------------
__global__ __launch_bounds__(256) void wpre_kernel(
    const float* __restrict__ Wt, ushort* __restrict__ wpre)
{
    const int g = blockIdx.x * 256 + threadIdx.x;   // 0 .. NCT*NK*64-1
    const int l = g & 63;
    const int t = (g >> 6) % NK;
    const int ct = g / (NK * 64);
    const int col = ct * 16 + (l & 15);
    const int k = t * 32 + (l >> 4) * 8;
    ushort4 h0 = {0, 0, 0, 0}, h1 = {0, 0, 0, 0};
    if (col < DENT) {
        h0 = cvt4(*(const float4*)(Wt + (size_t)col * DCTX + k));
        h1 = cvt4(*(const float4*)(Wt + (size_t)col * DCTX + k + 4));
    }
    *(ushort4*)(wpre + (size_t)g * 8)     = h0;
    *(ushort4*)(wpre + (size_t)g * 8 + 4) = h1;
}

// ---------------------------------------------------------------------------
// K1: proj = ctx @ proj_W.T + proj_b -- hybrid MFMA GEMM (R6/R9, proven).
// BM=64, 512 threads. A: f32->LDS dbuf, depth-2 reg prefetch. B: frag-direct.
// ---------------------------------------------------------------------------
#define GBM 64
#define LDA 40

__global__ __launch_bounds__(512) void gemm_proj_mfma(
    const float*  __restrict__ A,     // (16384, 768)
    const ushort* __restrict__ wpre,  // frag-major bf16 W
    const float*  __restrict__ bias,  // (300)
    float* __restrict__ out)          // (16384, 300)
{
    __shared__ ushort Al[2][GBM * LDA];
    const int tid = threadIdx.x;
    const int lane = tid & 63;
    const int wv = tid >> 6;
    const int wm = wv >> 2;          // 0..1
    const int wn = wv & 3;           // 0..3
    const int m0 = blockIdx.x * GBM;
    const int ar = tid >> 3;         // 0..63
    const int ak = (tid & 7) * 4;    // 0..28
    const int lr = lane & 15;
    const int kq = (lane >> 4) * 8;

    const float* aP = A + (size_t)(m0 + ar) * DCTX + ak;
    const ushort* bp = wpre + (size_t)wn * 5 * NK * 512 + (size_t)lane * 8;

    f32x4 acc[2][5];
    #pragma unroll
    for (int i = 0; i < 2; ++i)
        #pragma unroll
        for (int j = 0; j < 5; ++j)
            acc[i][j] = (f32x4){0.f, 0.f, 0.f, 0.f};

    bf16x8 cb[5], nb[5];
    #pragma unroll
    for (int j = 0; j < 5; ++j)
        cb[j] = *(const bf16x8*)(bp + (size_t)j * NK * 512);

#define STOREA(BUF, v_) (*(ushort4*)&Al[BUF][ar * LDA + ak] = cvt4(v_))

#define COMPUTE(BUF) do {                                                      \
        bf16x8 af_[2];                                                         \
        _Pragma("unroll")                                                      \
        for (int i_ = 0; i_ < 2; ++i_)                                         \
            af_[i_] = *(const bf16x8*)&Al[BUF][(wm*32 + i_*16 + lr)*LDA + kq]; \
        _Pragma("unroll")                                                      \
        for (int j_ = 0; j_ < 5; ++j_)                                         \
            acc[0][j_] = __builtin_amdgcn_mfma_f32_16x16x32_bf16(              \
                af_[0], cb[j_], acc[0][j_], 0, 0, 0);                          \
        _Pragma("unroll")                                                      \
        for (int j_ = 0; j_ < 5; ++j_)                                         \
            acc[1][j_] = __builtin_amdgcn_mfma_f32_16x16x32_bf16(              \
                af_[1], cb[j_], acc[1][j_], 0, 0, 0);                          \
    } while (0)

    float4 avA = *(const float4*)(aP);
    float4 avB = *(const float4*)(aP + 32);
    STOREA(0, avA);
    __syncthreads();

    #pragma unroll 1
    for (int kk = 0; kk < NK; kk += 2) {
        #pragma unroll
        for (int j = 0; j < 5; ++j)
            nb[j] = *(const bf16x8*)(bp + ((size_t)j * NK + kk + 1) * 512);
        if (kk + 2 < NK) avA = *(const float4*)(aP + (kk + 2) * 32);
        COMPUTE(0);
        STOREA(1, avB);
        __syncthreads();
        #pragma unroll
        for (int j = 0; j < 5; ++j) cb[j] = nb[j];
        if (kk + 2 < NK) {
            #pragma unroll
            for (int j = 0; j < 5; ++j)
                nb[j] = *(const bf16x8*)(bp + ((size_t)j * NK + kk + 2) * 512);
            avB = *(const float4*)(aP + (kk + 3) * 32);
        }
        COMPUTE(1);
        if (kk + 2 < NK) STOREA(0, avA);
        __syncthreads();
        #pragma unroll
        for (int j = 0; j < 5; ++j) cb[j] = nb[j];
    }

    const int lq = lane >> 4;
    #pragma unroll
    for (int j = 0; j < 5; ++j) {
        int col = wn * 80 + j * 16 + lr;
        if (col < DENT) {
            float bv = bias[col];
            #pragma unroll
            for (int i = 0; i < 2; ++i)
                #pragma unroll
                for (int r = 0; r < 4; ++r) {
                    int row = m0 + wm * 32 + i * 16 + lq * 4 + r;
                    out[(size_t)row * DENT + col] = acc[i][j][r] + bv;
                }
        }
    }
}

// ---------------------------------------------------------------------------
// K2: span extraction + LN (DPP reductions). 4 spans/block. (R9, proven)
// ---------------------------------------------------------------------------
__global__ __launch_bounds__(256) void span_kernel(
    const float* __restrict__ proj,     // (B*T, 300)
    const int*   __restrict__ spans,    // (B*S, 2)
    const float* __restrict__ attn_W,   // (300)
    const float* __restrict__ attn_b,   // (1)
    const float* __restrict__ ln_g,
    const float* __restrict__ ln_b,
    const float* __restrict__ kg_g,
    const float* __restrict__ kg_b,
    float* __restrict__ srg_out,        // (B*S, 300)
    float* __restrict__ sgsb)           // (B*S, 2)
{
    const int bs = blockIdx.x * 4 + (threadIdx.x >> 6);
    const int b = bs >> 7;   // SS = 128
    const int lane = threadIdx.x & 63;
    const int start = spans[bs * 2 + 0];
    const int end   = spans[bs * 2 + 1];
    const int width = end - start;
    const bool lo = lane < 11;
    const float4 z = make_float4(0.f, 0.f, 0.f, 0.f);

    const float4* attW4 = (const float4*)attn_W;
    float4 w0 = attW4[lane];
    float4 w1 = lo ? attW4[64 + lane] : z;

    float4 a0[WW], a1[WW];
    float slog[WW];
    bool vld[WW];
    #pragma unroll
    for (int w = 0; w < WW; ++w) {
        int idx = start + w;
        vld[w] = (w <= width) && (idx >= 0) && (idx < TT);
        const float4* pr = (const float4*)(proj + (size_t)(b * TT + (vld[w] ? idx : 0)) * DENT);
        a0[w] = pr[lane];
        a1[w] = lo ? pr[64 + lane] : z;
        slog[w] = dot4(a0[w], w0) + dot4(a1[w], w1);
    }
    const float ab = attn_b[0];
    #pragma unroll
    for (int w = 0; w < WW; ++w) {
        float r = wave_red(slog[w]);
        slog[w] = vld[w] ? r + ab : NEGF;
    }
    float m = slog[0];
    #pragma unroll
    for (int w = 1; w < WW; ++w) m = fmaxf(m, slog[w]);
    float den = 0.f;
    float aw[WW];
    #pragma unroll
    for (int w = 0; w < WW; ++w) { aw[w] = expf(slog[w] - m); den += aw[w]; }
    const float inv = 1.f / den;
    const float msk = (start > -1) ? inv : 0.f;

    float4 acc0 = z, acc1 = z;
    #pragma unroll
    for (int w = 0; w < WW; ++w) {
        float c = aw[w] * msk;
        acc0.x = fmaf(c, a0[w].x, acc0.x); acc0.y = fmaf(c, a0[w].y, acc0.y);
        acc0.z = fmaf(c, a0[w].z, acc0.z); acc0.w = fmaf(c, a0[w].w, acc0.w);
        acc1.x = fmaf(c, a1[w].x, acc1.x); acc1.y = fmaf(c, a1[w].y, acc1.y);
        acc1.z = fmaf(c, a1[w].z, acc1.z); acc1.w = fmaf(c, a1[w].w, acc1.w);
    }
    float s1 = wave_red(hadd8(acc0, acc1));
    float s2 = wave_red(dot4(acc0, acc0) + dot4(acc1, acc1));
    const float mu = s1 * (1.f / DENT);
    const float rstd = rsqrtf(s2 * (1.f / DENT) - mu * mu + EPSF);

    const float4* lg4 = (const float4*)ln_g;  const float4* lb4 = (const float4*)ln_b;
    const float4* gg4 = (const float4*)kg_g;  const float4* gb4 = (const float4*)kg_b;
    float pg = 0.f, pb = 0.f;
    float4* so = (float4*)(srg_out + (size_t)bs * DENT);
    {
        float4 g = lg4[lane], bb_ = lb4[lane], gg = gg4[lane], gb = gb4[lane];
        float4 val;
        val.x = fmaf((acc0.x - mu) * rstd, g.x, bb_.x);
        val.y = fmaf((acc0.y - mu) * rstd, g.y, bb_.y);
        val.z = fmaf((acc0.z - mu) * rstd, g.z, bb_.z);
        val.w = fmaf((acc0.w - mu) * rstd, g.w, bb_.w);
        float4 vg = make_float4(val.x * gg.x, val.y * gg.y, val.z * gg.z, val.w * gg.w);
        so[lane] = vg;
        pg += vg.x + vg.y + vg.z + vg.w;
        pb += val.x * gb.x + val.y * gb.y + val.z * gb.z + val.w * gb.w;
    }
    if (lo) {
        float4 g = lg4[64 + lane], bb_ = lb4[64 + lane], gg = gg4[64 + lane], gb = gb4[64 + lane];
        float4 val;
        val.x = fmaf((acc1.x - mu) * rstd, g.x, bb_.x);
        val.y = fmaf((acc1.y - mu) * rstd, g.y, bb_.y);
        val.z = fmaf((acc1.z - mu) * rstd, g.z, bb_.z);
        val.w = fmaf((acc1.w - mu) * rstd, g.w, bb_.w);
        float4 vg = make_float4(val.x * gg.x, val.y * gg.y, val.z * gg.z, val.w * gg.w);
        so[64 + lane] = vg;
        pg += vg.x + vg.y + vg.z + vg.w;
        pb += val.x * gb.x + val.y * gb.y + val.z * gb.z + val.w * gb.w;
    }
    pg = wave_red(pg);
    pb = wave_red(pb);
    if (lane == 0) { sgsb[bs * 2 + 0] = pg; sgsb[bs * 2 + 1] = pb; }
}

// ---------------------------------------------------------------------------
// K3: fused scores + softmax + weighted sum. R9 structure, but entity rows
// are DMA'd straight to LDS (global_load_lds, no VGPR round-trip) and the
// reduce phase re-reads them from LDS sequentially per candidate: block
// VGPR drops ~90 -> <=64, so 4 blocks/CU co-reside (LDS-capped) and other
// blocks' DMA overlaps this block's compute.
// ---------------------------------------------------------------------------
__global__ __launch_bounds__(512, 8) void final_fused(
    const float* __restrict__ srg,      // (B*S, 300)
    const float* __restrict__ sgsb,     // (B*S, 2)
    const int*   __restrict__ cand,     // (B*S*30)
    const float* __restrict__ priors,   // (B*S*30)
    const float* __restrict__ table,    // (V, 300)
    const float* __restrict__ W1,       // (100,2)
    const float* __restrict__ b1,       // (100)
    const float* __restrict__ W2,       // (100)
    const float* __restrict__ b2,       // (1)
    const float* __restrict__ kg_g,
    const float* __restrict__ kg_b,
    float* __restrict__ out_link,       // (B*S*30)
    float* __restrict__ out_w)          // (B*S, 300)
{
    __shared__ float rows[CC][DENT];            // 36000 B
    __shared__ float smu[CC], srs[CC], ssc[CC], sexp[CC];
    const int bs = blockIdx.x;
    const int tid = threadIdx.x;
    const int lane = tid & 63;
    const int wv = tid >> 6;
    const bool lo = lane < 11;
    const float4 z = make_float4(0.f, 0.f, 0.f, 0.f);

    // ---- DMA the wave's 3-4 entity rows straight to LDS -------------------
    int es[4] = {0, 0, 0, 0};
    #pragma unroll
    for (int k = 0; k < 4; ++k) {
        int c = wv + k * 8;
        if (c < CC) {
            int e = cand[bs * CC + c];
            es[k] = e;
            const float* src = table + (size_t)e * DENT;
            dma16(src + lane * 4, &rows[c][0]);          // floats 0..255
            if (lo) dma16(src + 256 + lane * 4, &rows[c][256]);  // 256..299
        }
    }

    // ---- per-bs vectors & MLP weights (registers, small) ------------------
    const float4* sg4 = (const float4*)(srg + (size_t)bs * DENT);
    float4 g0 = sg4[lane];
    float4 g1 = lo ? sg4[64 + lane] : z;
    const float SG = sgsb[bs * 2 + 0];
    const float SB = sgsb[bs * 2 + 1];
    const float W1a0 = W1[2 * lane], W1b0 = W1[2 * lane + 1];
    const float B10 = b1[lane], W20 = W2[lane];
    float W1a1 = 0.f, W1b1 = 0.f, B11 = 0.f, W21 = 0.f;
    if (lane < HH - 64) {
        int j = lane + 64;
        W1a1 = W1[2 * j]; W1b1 = W1[2 * j + 1]; B11 = b1[j]; W21 = W2[j];
    }
    const float b2v = b2[0];
    const float isd = rsqrtf((float)DENT);

    __syncthreads();   // drains DMA (vmcnt) -> rows resident in LDS

    // ---- sequential per-candidate reduce from LDS (low VGPR) ---------------
    #pragma unroll
    for (int k = 0; k < 4; ++k) {
        int c = wv + k * 8;
        if (c < CC) {
            float4 xa = *(const float4*)&rows[c][lane * 4];
            float4 xb = lo ? *(const float4*)&rows[c][256 + lane * 4] : z;
            float s1 = wave_red(hadd8(xa, xb));
            float s2 = wave_red(dot4(xa, xa) + dot4(xb, xb));
            float s3 = wave_red(dot4(g0, xa) + dot4(g1, xb));
            float mu = s1 * (1.f / DENT);
            float rstd = rsqrtf(s2 * (1.f / DENT) - mu * mu + EPSF);
            float score = (rstd * (s3 - mu * SG) + SB) * isd;
            float pr = priors[bs * CC + c];
            float h  = fmaxf(fmaf(W1a0, score, fmaf(W1b0, pr, B10)), 0.f);
            float h2 = fmaxf(fmaf(W1a1, score, fmaf(W1b1, pr, B11)), 0.f);
            float lp = wave_red(fmaf(W21, h2, W20 * h)) + b2v;
            float link = (es[k] > 0) ? lp : -10000.0f;
            if (lane == 0) {
                smu[c] = mu; srs[c] = rstd; ssc[c] = link;
                out_link[bs * CC + c] = link;
            }
        }
    }
    __syncthreads();

    if (tid < CC) {
        float m = ssc[0];
        #pragma unroll
        for (int c = 1; c < CC; ++c) m = fmaxf(m, ssc[c]);
        sexp[tid] = expf(ssc[tid] - m);
    }
    __syncthreads();

    const int d = tid;
    if (d < DENT) {
        float den = 0.f;
        #pragma unroll
        for (int c = 0; c < CC; ++c) den += sexp[c];
        const float inv = 1.f / den;
        float acc = 0.f, S2 = 0.f, sn = 0.f;
        #pragma unroll
        for (int c = 0; c < CC; ++c) {
            float n = sexp[c] * inv;
            float coef = n * srs[c];
            acc = fmaf(coef, rows[c][d], acc);
            S2 = fmaf(coef, smu[c], S2);
            sn += n;
        }
        out_w[(size_t)bs * DENT + d] = kg_g[d] * (acc - S2) + kg_b[d] * sn;
    }
}

extern "C" void kernel_launch(void* const* d_in, const int* in_sizes, int n_in,
                              void* d_out, int out_size, void* d_ws, size_t ws_size,
                              hipStream_t stream) {
    const float* ctx    = (const float*)d_in[0];
    const int*   spans  = (const int*)d_in[2];
    const int*   cand   = (const int*)d_in[3];
    const float* priors = (const float*)d_in[4];
    const float* table  = (const float*)d_in[6];
    const float* projW  = (const float*)d_in[7];
    const float* projb  = (const float*)d_in[8];
    const float* kg_g   = (const float*)d_in[9];
    const float* kg_b   = (const float*)d_in[10];
    const float* ln_g   = (const float*)d_in[11];
    const float* ln_b   = (const float*)d_in[12];
    const float* attW   = (const float*)d_in[13];
    const float* attb   = (const float*)d_in[14];
    const float* W1     = (const float*)d_in[15];
    const float* b1     = (const float*)d_in[16];
    const float* W2     = (const float*)d_in[17];
    const float* b2     = (const float*)d_in[18];

    float* proj = (float*)d_ws;                           // (B*T, 300)
    float* srg  = proj + (size_t)BB * TT * DENT;          // (B*S, 300)
    float* sgsb = srg + (size_t)BB * SS * DENT;           // (B*S, 2)
    // wpre (492 KB) aliases srg: consumed by gemm before span writes srg.
    ushort* wpre = (ushort*)srg;

    float* out_link = (float*)d_out;                      // (B*S*30)
    float* out_w    = out_link + (size_t)BB * SS * CC;    // (B*S, 300)

    wpre_kernel<<<NCT * NK * 64 / 256, 256, 0, stream>>>(projW, wpre);
    gemm_proj_mfma<<<BB * TT / GBM, 512, 0, stream>>>(ctx, wpre, projb, proj);
    span_kernel<<<BB * SS / 4, 256, 0, stream>>>(proj, spans, attW, attb,
                                                 ln_g, ln_b, kg_g, kg_b, srg, sgsb);
    final_fused<<<BB * SS, 512, 0, stream>>>(srg, sgsb, cand, priors, table,
                                             W1, b1, W2, b2, kg_g, kg_b,
                                             out_link, out_w);
}